// Round 1
// baseline (1994.769 us; speedup 1.0000x reference)
//
#include <hip/hip_runtime.h>

#define T_STEPS 512
#define BATCH   512
#define HID     128

typedef _Float16 h2 __attribute__((ext_vector_type(2)));
typedef _Float16 h4 __attribute__((ext_vector_type(4)));
typedef _Float16 h8 __attribute__((ext_vector_type(8)));

union U8 { h8 v8; h2 v2[4]; };

__device__ __forceinline__ float fdot2(h2 a, h2 b, float c) {
#if __has_builtin(__builtin_amdgcn_fdot2)
  return __builtin_amdgcn_fdot2(a, b, c, false);
#else
  return c + (float)a[0]*(float)b[0] + (float)a[1]*(float)b[1];
#endif
}

__device__ __forceinline__ float sigm(float x)  { return 1.0f / (1.0f + __expf(-x)); }
// safe tanh: no overflow/NaN for large |x|
__device__ __forceinline__ float tanh_f(float x){ return 1.0f - 2.0f / (__expf(2.0f * x) + 1.0f); }

// dot over N8*8 halfs at VPTR against register array w[], 4 accumulators
#define DOT_SLICE(VPTR, N8, OUT) do {                                        \
    const h8* vv_ = (const h8*)(VPTR);                                       \
    float a0_=0.f, a1_=0.f, a2_=0.f, a3_=0.f;                                \
    _Pragma("unroll")                                                        \
    for (int i_ = 0; i_ < (N8); ++i_) {                                      \
      U8 u_; u_.v8 = vv_[i_];                                                \
      a0_ = fdot2(w[4*i_+0], u_.v2[0], a0_);                                 \
      a1_ = fdot2(w[4*i_+1], u_.v2[1], a1_);                                 \
      a2_ = fdot2(w[4*i_+2], u_.v2[2], a2_);                                 \
      a3_ = fdot2(w[4*i_+3], u_.v2[3], a3_);                                 \
    }                                                                        \
    OUT = (a0_ + a1_) + (a2_ + a3_);                                         \
  } while (0)

// ---------------------------------------------------------------- prep ----
__global__ __launch_bounds__(256) void prep_x(const float* __restrict__ x,
                                              _Float16* __restrict__ xh, int n4) {
  int i = blockIdx.x * blockDim.x + threadIdx.x;
  if (i < n4) {
    float4 v = ((const float4*)x)[i];
    h4 o; o[0] = (_Float16)v.x; o[1] = (_Float16)v.y;
          o[2] = (_Float16)v.z; o[3] = (_Float16)v.w;
    ((h4*)xh)[i] = o;
  }
}

__global__ __launch_bounds__(256) void prep_w(
    const float* __restrict__ Wih0, const float* __restrict__ Whh0,
    const float* __restrict__ bih0, const float* __restrict__ bhh0,
    const float* __restrict__ Wih1, const float* __restrict__ Whh1,
    const float* __restrict__ bih1, const float* __restrict__ bhh1,
    _Float16* __restrict__ Wcat0, _Float16* __restrict__ Wcat1,
    float* __restrict__ bias0, float* __restrict__ bias1) {
  int i = blockIdx.x * blockDim.x + threadIdx.x;
  if (i < 512 * 192) {                  // Wcat0 row r: [Wih0(64) | Whh0(128)]
    int r = i / 192, k = i - r * 192;
    float v = (k < 64) ? Wih0[r * 64 + k] : Whh0[r * 128 + (k - 64)];
    Wcat0[i] = (_Float16)v;
  }
  if (i < 512 * 256) {                  // Wcat1 row r: [Wih1(128) | Whh1(128)]
    int r = i >> 8, k = i & 255;
    float v = (k < 128) ? Wih1[r * 128 + k] : Whh1[r * 128 + (k - 128)];
    Wcat1[i] = (_Float16)v;
  }
  if (i < 512) {
    bias0[i] = bih0[i] + bhh0[i];
    bias1[i] = bih1[i] + bhh1[i];
  }
}

// ------------------------------------------------------------- layer 0 ----
// 256 blocks x 1024 threads; block handles chains b0, b0+1.
// thread (r = tid>>1, p = tid&1): gate row r, input slice p of v = [x(64)|h(128)]
__global__ __launch_bounds__(1024, 4) void lstm_l0(
    const _Float16* __restrict__ xh,    // [B][T][64]
    const _Float16* __restrict__ Wcat,  // [512][192]
    const float*    __restrict__ bias,  // [512]
    _Float16*       __restrict__ hs0) { // [B][T][128]
  __shared__ __align__(16) _Float16 vbuf[2][192];  // [chain][ x(64) | h(128) ]
  __shared__ float gbuf[2][512];
  const int tid = threadIdx.x;
  const int r = tid >> 1, p = tid & 1;
  const int b0 = blockIdx.x * 2;

  h2 w[48];
  {
    const h8* wp = (const h8*)(Wcat + r * 192 + p * 96);
    #pragma unroll
    for (int i = 0; i < 12; ++i) {
      U8 u; u.v8 = wp[i];
      #pragma unroll
      for (int j = 0; j < 4; ++j) w[i * 4 + j] = u.v2[j];
    }
  }
  const float bb = bias[r];
  const int sc = tid >> 7, sd = tid & 127;   // state mapping for tid<256

  if (tid < 256) vbuf[sc][64 + sd] = (_Float16)0.0f;   // h(0) = 0
  if (tid < 64) {                                      // x(0)
    const int ch = tid >> 5, l = tid & 31;
    *(h2*)&vbuf[ch][l * 2] =
        *(const h2*)&xh[((size_t)(b0 + ch) * T_STEPS) * 64 + l * 2];
  }
  __syncthreads();

  float c_state = 0.0f;

  for (int t = 0; t < T_STEPS; ++t) {
    // prefetch x(t+1) into a register (1 wave), consumed after barrier 1
    h2 xreg;
    const bool pf = (tid < 64) && (t + 1 < T_STEPS);
    if (pf) {
      const int ch = tid >> 5, l = tid & 31;
      xreg = *(const h2*)&xh[((size_t)(b0 + ch) * T_STEPS + (t + 1)) * 64 + l * 2];
    }
    float s0, s1;
    DOT_SLICE(&vbuf[0][p * 96], 12, s0);
    DOT_SLICE(&vbuf[1][p * 96], 12, s1);
    s0 += __shfl_xor(s0, 1);
    s1 += __shfl_xor(s1, 1);
    if (p == 0) { gbuf[0][r] = s0 + bb; gbuf[1][r] = s1 + bb; }
    __syncthreads();                       // gates visible; vbuf reads done
    if (pf) {
      const int ch = tid >> 5, l = tid & 31;
      *(h2*)&vbuf[ch][l * 2] = xreg;
    }
    if (tid < 256) {
      const float gi = gbuf[sc][sd];
      const float gf = gbuf[sc][HID + sd];
      const float gg = gbuf[sc][2 * HID + sd];
      const float go = gbuf[sc][3 * HID + sd];
      c_state = sigm(gf) * c_state + sigm(gi) * tanh_f(gg);
      const float hval = sigm(go) * tanh_f(c_state);
      const _Float16 hh = (_Float16)hval;
      vbuf[sc][64 + sd] = hh;
      hs0[((size_t)(b0 + sc) * T_STEPS + t) * HID + sd] = hh;
    }
    __syncthreads();                       // new x/h visible
  }
}

// ------------------------------------------------------------- layer 1 ----
// v = [h0(128) | h1(128)]
__global__ __launch_bounds__(1024, 4) void lstm_l1(
    const _Float16* __restrict__ hs0,   // [B][T][128]
    const _Float16* __restrict__ Wcat,  // [512][256]
    const float*    __restrict__ bias,  // [512]
    float*          __restrict__ h2last) { // [B][128] fp32
  __shared__ __align__(16) _Float16 vbuf[2][256];
  __shared__ float gbuf[2][512];
  const int tid = threadIdx.x;
  const int r = tid >> 1, p = tid & 1;
  const int b0 = blockIdx.x * 2;

  h2 w[64];
  {
    const h8* wp = (const h8*)(Wcat + r * 256 + p * 128);
    #pragma unroll
    for (int i = 0; i < 16; ++i) {
      U8 u; u.v8 = wp[i];
      #pragma unroll
      for (int j = 0; j < 4; ++j) w[i * 4 + j] = u.v2[j];
    }
  }
  const float bb = bias[r];
  const int sc = tid >> 7, sd = tid & 127;

  if (tid < 256) vbuf[sc][HID + sd] = (_Float16)0.0f;  // h1(0) = 0
  if (tid < 64) {                                      // h0(0)
    const int ch = tid >> 5, l = tid & 31;
    *(h4*)&vbuf[ch][l * 4] =
        *(const h4*)&hs0[((size_t)(b0 + ch) * T_STEPS) * HID + l * 4];
  }
  __syncthreads();

  float c_state = 0.0f;

  for (int t = 0; t < T_STEPS; ++t) {
    h4 hreg;
    const bool pf = (tid < 64) && (t + 1 < T_STEPS);
    if (pf) {
      const int ch = tid >> 5, l = tid & 31;
      hreg = *(const h4*)&hs0[((size_t)(b0 + ch) * T_STEPS + (t + 1)) * HID + l * 4];
    }
    float s0, s1;
    DOT_SLICE(&vbuf[0][p * 128], 16, s0);
    DOT_SLICE(&vbuf[1][p * 128], 16, s1);
    s0 += __shfl_xor(s0, 1);
    s1 += __shfl_xor(s1, 1);
    if (p == 0) { gbuf[0][r] = s0 + bb; gbuf[1][r] = s1 + bb; }
    __syncthreads();
    if (pf) {
      const int ch = tid >> 5, l = tid & 31;
      *(h4*)&vbuf[ch][l * 4] = hreg;
    }
    if (tid < 256) {
      const float gi = gbuf[sc][sd];
      const float gf = gbuf[sc][HID + sd];
      const float gg = gbuf[sc][2 * HID + sd];
      const float go = gbuf[sc][3 * HID + sd];
      c_state = sigm(gf) * c_state + sigm(gi) * tanh_f(gg);
      const float hval = sigm(go) * tanh_f(c_state);
      vbuf[sc][HID + sd] = (_Float16)hval;
      if (t == T_STEPS - 1) h2last[(size_t)(b0 + sc) * HID + sd] = hval;
    }
    __syncthreads();
  }
}

// ------------------------------------------------------------- fc head ----
__global__ __launch_bounds__(128) void fc_head(
    const float* __restrict__ h2last, const float* __restrict__ fc1w,
    const float* __restrict__ fc1b, const float* __restrict__ fc2w,
    const float* __restrict__ fc2b, float* __restrict__ out) {
  __shared__ float hb[128];
  __shared__ float part[2];
  const int b = blockIdx.x, j = threadIdx.x;
  hb[j] = h2last[(size_t)b * HID + j];
  __syncthreads();
  const float* wr = fc1w + j * HID;
  float acc = 0.f;
  #pragma unroll 8
  for (int d = 0; d < HID; ++d) acc += wr[d] * hb[d];
  float v = fmaxf(acc + fc1b[j], 0.f) * fc2w[j];
  #pragma unroll
  for (int s = 32; s > 0; s >>= 1) v += __shfl_down(v, s);
  if ((j & 63) == 0) part[j >> 6] = v;
  __syncthreads();
  if (j == 0) out[b] = part[0] + part[1] + fc2b[0];
}

// -------------------------------------------------------------- launch ----
extern "C" void kernel_launch(void* const* d_in, const int* in_sizes, int n_in,
                              void* d_out, int out_size, void* d_ws, size_t ws_size,
                              hipStream_t stream) {
  const float* x    = (const float*)d_in[0];
  const float* Wih0 = (const float*)d_in[1];
  const float* Whh0 = (const float*)d_in[2];
  const float* bih0 = (const float*)d_in[3];
  const float* bhh0 = (const float*)d_in[4];
  const float* Wih1 = (const float*)d_in[5];
  const float* Whh1 = (const float*)d_in[6];
  const float* bih1 = (const float*)d_in[7];
  const float* bhh1 = (const float*)d_in[8];
  const float* fc1w = (const float*)d_in[9];
  const float* fc1b = (const float*)d_in[10];
  const float* fc2w = (const float*)d_in[11];
  const float* fc2b = (const float*)d_in[12];
  float* out = (float*)d_out;

  char* ws = (char*)d_ws;
  const size_t OFF_XH    = 0;                       // 512*512*64*2  = 32 MiB
  const size_t OFF_HS0   = 33554432;                // 512*512*128*2 = 64 MiB
  const size_t OFF_WC0   = OFF_HS0 + 67108864;      // 512*192*2
  const size_t OFF_WC1   = OFF_WC0 + 196608;        // 512*256*2
  const size_t OFF_B0    = OFF_WC1 + 262144;        // 512*4
  const size_t OFF_B1    = OFF_B0 + 2048;
  const size_t OFF_H2L   = OFF_B1 + 2048;           // 512*128*4

  _Float16* xh     = (_Float16*)(ws + OFF_XH);
  _Float16* hs0    = (_Float16*)(ws + OFF_HS0);
  _Float16* Wcat0  = (_Float16*)(ws + OFF_WC0);
  _Float16* Wcat1  = (_Float16*)(ws + OFF_WC1);
  float*    bias0  = (float*)(ws + OFF_B0);
  float*    bias1  = (float*)(ws + OFF_B1);
  float*    h2last = (float*)(ws + OFF_H2L);

  prep_x<<<16384, 256, 0, stream>>>(x, xh, 512 * 512 * 64 / 4);
  prep_w<<<512, 256, 0, stream>>>(Wih0, Whh0, bih0, bhh0, Wih1, Whh1, bih1, bhh1,
                                  Wcat0, Wcat1, bias0, bias1);
  lstm_l0<<<256, 1024, 0, stream>>>(xh, Wcat0, bias0, hs0);
  lstm_l1<<<256, 1024, 0, stream>>>(hs0, Wcat1, bias1, h2last);
  fc_head<<<512, 128, 0, stream>>>(h2last, fc1w, fc1b, fc2w, fc2b, out);
}

// Round 2
// 1158.318 us; speedup vs baseline: 1.7221x; 1.7221x over previous
//
#include <hip/hip_runtime.h>

#define T_STEPS 512
#define BATCH   512
#define HID     128

typedef _Float16 h2 __attribute__((ext_vector_type(2)));
typedef _Float16 h4 __attribute__((ext_vector_type(4)));
typedef _Float16 v8hf __attribute__((ext_vector_type(8)));
typedef float v4f __attribute__((ext_vector_type(4)));

__device__ __forceinline__ float sigm(float x)  { return 1.0f / (1.0f + __expf(-x)); }
__device__ __forceinline__ float tanh_f(float x){ return 1.0f - 2.0f / (__expf(2.0f * x) + 1.0f); }

// ---------------------------------------------------------------- prep ----
__global__ __launch_bounds__(256) void prep_x(const float* __restrict__ x,
                                              _Float16* __restrict__ xh, int n4) {
  int i = blockIdx.x * blockDim.x + threadIdx.x;
  if (i < n4) {
    float4 v = ((const float4*)x)[i];
    h4 o; o[0] = (_Float16)v.x; o[1] = (_Float16)v.y;
          o[2] = (_Float16)v.z; o[3] = (_Float16)v.w;
    ((h4*)xh)[i] = o;
  }
}

__global__ __launch_bounds__(256) void prep_w(
    const float* __restrict__ Wih0, const float* __restrict__ Whh0,
    const float* __restrict__ bih0, const float* __restrict__ bhh0,
    const float* __restrict__ Wih1, const float* __restrict__ Whh1,
    const float* __restrict__ bih1, const float* __restrict__ bhh1,
    _Float16* __restrict__ Wcat0, _Float16* __restrict__ Wcat1,
    float* __restrict__ bias0, float* __restrict__ bias1) {
  int i = blockIdx.x * blockDim.x + threadIdx.x;
  if (i < 512 * 192) {                  // Wcat0 row r: [Wih0(64) | Whh0(128)]
    int r = i / 192, k = i - r * 192;
    float v = (k < 64) ? Wih0[r * 64 + k] : Whh0[r * 128 + (k - 64)];
    Wcat0[i] = (_Float16)v;
  }
  if (i < 512 * 256) {                  // Wcat1 row r: [Wih1(128) | Whh1(128)]
    int r = i >> 8, k = i & 255;
    float v = (k < 128) ? Wih1[r * 128 + k] : Whh1[r * 128 + (k - 128)];
    Wcat1[i] = (_Float16)v;
  }
  if (i < 512) {
    bias0[i] = bih0[i] + bhh0[i];
    bias1[i] = bih1[i] + bhh1[i];
  }
}

// ------------------------------------------------------------- layer 0 ----
// 256 blocks x 512 threads (8 waves), 2 chains/block.
// Wave w holds A-frags for row-tiles {4w..4w+3} x 6 k-tiles in VGPRs.
// MFMA B-operand: col(=lane&15) 0/1 = chain 0/1; v = [x(64)|h(128)], K=192.
__global__ __launch_bounds__(512, 2) void lstm_l0(
    const _Float16* __restrict__ xh,    // [B][T][64]
    const _Float16* __restrict__ Wcat,  // [512][192]
    const float*    __restrict__ bias,  // [512]
    _Float16*       __restrict__ hs0) { // [B][T][128]
  __shared__ __align__(16) _Float16 vbuf[2][192];  // [chain][ x(64) | h(128) ]
  __shared__ __align__(16) float gbuf[2][512];
  const int tid  = threadIdx.x;
  const int lane = tid & 63;
  const int wv   = tid >> 6;          // 0..7
  const int m    = lane & 15;         // A row within tile / B col (chain)
  const int q    = lane >> 4;         // k-group: k = q*8 + j
  const int b0   = blockIdx.x * 2;

  // A fragments: af[i][kt], rt = 4*wv + i, K=192 (6 k-tiles)
  v8hf af[4][6];
  #pragma unroll
  for (int i = 0; i < 4; ++i) {
    const int rt = wv * 4 + i;
    #pragma unroll
    for (int kt = 0; kt < 6; ++kt)
      af[i][kt] = *(const v8hf*)&Wcat[(rt * 16 + m) * 192 + kt * 32 + q * 8];
  }

  const int sc = tid >> 7, sd = tid & 127;   // state mapping (tid<256)
  float bi = 0.f, bf = 0.f, bg = 0.f, bo = 0.f;
  if (tid < 256) {
    bi = bias[sd]; bf = bias[128 + sd]; bg = bias[256 + sd]; bo = bias[384 + sd];
    vbuf[sc][64 + sd] = (_Float16)0.0f;      // h(0) = 0
  }
  // x(0): 16 lanes load 8 halfs each
  if (tid >= 256 && tid < 272) {
    const int ch = (tid >> 3) & 1, l = tid & 7;
    *(v8hf*)&vbuf[ch][l * 8] =
        *(const v8hf*)&xh[((size_t)(b0 + ch) * T_STEPS) * 64 + l * 8];
  }
  __syncthreads();

  float c_state = 0.0f;
  const v4f zc = {0.f, 0.f, 0.f, 0.f};
  const v8hf zb = {0, 0, 0, 0, 0, 0, 0, 0};

  for (int t = 0; t < T_STEPS; ++t) {
    // prefetch x(t+1) into registers (wave 4 lanes), written after barrier 1
    v8hf xreg;
    const bool pf = (tid >= 256 && tid < 272) && (t + 1 < T_STEPS);
    if (pf) {
      const int ch = (tid >> 3) & 1, l = tid & 7;
      xreg = *(const v8hf*)&xh[((size_t)(b0 + ch) * T_STEPS + (t + 1)) * 64 + l * 8];
    }

    v4f acc[4];
    #pragma unroll
    for (int kt = 0; kt < 6; ++kt) {
      v8hf bfr = (m < 2) ? *(const v8hf*)&vbuf[m][kt * 32 + q * 8] : zb;
      #pragma unroll
      for (int i = 0; i < 4; ++i)
        acc[i] = __builtin_amdgcn_mfma_f32_16x16x32_f16(
            af[i][kt], bfr, (kt == 0) ? zc : acc[i], 0, 0, 0);
    }
    if (m < 2) {
      #pragma unroll
      for (int i = 0; i < 4; ++i) {
        float4 o; o.x = acc[i][0]; o.y = acc[i][1]; o.z = acc[i][2]; o.w = acc[i][3];
        *(float4*)&gbuf[m][(wv * 4 + i) * 16 + q * 4] = o;
      }
    }
    __syncthreads();                       // gates visible; vbuf reads done
    if (pf) {
      const int ch = (tid >> 3) & 1, l = tid & 7;
      *(v8hf*)&vbuf[ch][l * 8] = xreg;
    }
    if (tid < 256) {
      const float gi = gbuf[sc][sd]        + bi;
      const float gf = gbuf[sc][HID + sd]  + bf;
      const float gg = gbuf[sc][2*HID + sd] + bg;
      const float go = gbuf[sc][3*HID + sd] + bo;
      c_state = sigm(gf) * c_state + sigm(gi) * tanh_f(gg);
      const float hval = sigm(go) * tanh_f(c_state);
      const _Float16 hh = (_Float16)hval;
      vbuf[sc][64 + sd] = hh;
      hs0[((size_t)(b0 + sc) * T_STEPS + t) * HID + sd] = hh;
    }
    __syncthreads();                       // new x/h visible
  }
}

// ------------------------------------------------------------- layer 1 ----
// v = [h0(128) | h1(128)], K=256 (8 k-tiles)
__global__ __launch_bounds__(512, 2) void lstm_l1(
    const _Float16* __restrict__ hs0,   // [B][T][128]
    const _Float16* __restrict__ Wcat,  // [512][256]
    const float*    __restrict__ bias,  // [512]
    float*          __restrict__ h2last) { // [B][128] fp32
  __shared__ __align__(16) _Float16 vbuf[2][256];
  __shared__ __align__(16) float gbuf[2][512];
  const int tid  = threadIdx.x;
  const int lane = tid & 63;
  const int wv   = tid >> 6;
  const int m    = lane & 15;
  const int q    = lane >> 4;
  const int b0   = blockIdx.x * 2;

  v8hf af[4][8];
  #pragma unroll
  for (int i = 0; i < 4; ++i) {
    const int rt = wv * 4 + i;
    #pragma unroll
    for (int kt = 0; kt < 8; ++kt)
      af[i][kt] = *(const v8hf*)&Wcat[(rt * 16 + m) * 256 + kt * 32 + q * 8];
  }

  const int sc = tid >> 7, sd = tid & 127;
  float bi = 0.f, bf = 0.f, bg = 0.f, bo = 0.f;
  if (tid < 256) {
    bi = bias[sd]; bf = bias[128 + sd]; bg = bias[256 + sd]; bo = bias[384 + sd];
    vbuf[sc][HID + sd] = (_Float16)0.0f;   // h1(0) = 0
  }
  if (tid >= 256 && tid < 288) {           // h0(0): 32 lanes x 8 halfs
    const int ch = (tid >> 4) & 1, l = tid & 15;
    *(v8hf*)&vbuf[ch][l * 8] =
        *(const v8hf*)&hs0[((size_t)(b0 + ch) * T_STEPS) * HID + l * 8];
  }
  __syncthreads();

  float c_state = 0.0f;
  const v4f zc = {0.f, 0.f, 0.f, 0.f};
  const v8hf zb = {0, 0, 0, 0, 0, 0, 0, 0};

  for (int t = 0; t < T_STEPS; ++t) {
    v8hf hreg;
    const bool pf = (tid >= 256 && tid < 288) && (t + 1 < T_STEPS);
    if (pf) {
      const int ch = (tid >> 4) & 1, l = tid & 15;
      hreg = *(const v8hf*)&hs0[((size_t)(b0 + ch) * T_STEPS + (t + 1)) * HID + l * 8];
    }

    v4f acc[4];
    #pragma unroll
    for (int kt = 0; kt < 8; ++kt) {
      v8hf bfr = (m < 2) ? *(const v8hf*)&vbuf[m][kt * 32 + q * 8] : zb;
      #pragma unroll
      for (int i = 0; i < 4; ++i)
        acc[i] = __builtin_amdgcn_mfma_f32_16x16x32_f16(
            af[i][kt], bfr, (kt == 0) ? zc : acc[i], 0, 0, 0);
    }
    if (m < 2) {
      #pragma unroll
      for (int i = 0; i < 4; ++i) {
        float4 o; o.x = acc[i][0]; o.y = acc[i][1]; o.z = acc[i][2]; o.w = acc[i][3];
        *(float4*)&gbuf[m][(wv * 4 + i) * 16 + q * 4] = o;
      }
    }
    __syncthreads();
    if (pf) {
      const int ch = (tid >> 4) & 1, l = tid & 15;
      *(v8hf*)&vbuf[ch][l * 8] = hreg;
    }
    if (tid < 256) {
      const float gi = gbuf[sc][sd]        + bi;
      const float gf = gbuf[sc][HID + sd]  + bf;
      const float gg = gbuf[sc][2*HID + sd] + bg;
      const float go = gbuf[sc][3*HID + sd] + bo;
      c_state = sigm(gf) * c_state + sigm(gi) * tanh_f(gg);
      const float hval = sigm(go) * tanh_f(c_state);
      vbuf[sc][HID + sd] = (_Float16)hval;
      if (t == T_STEPS - 1) h2last[(size_t)(b0 + sc) * HID + sd] = hval;
    }
    __syncthreads();
  }
}

// ------------------------------------------------------------- fc head ----
__global__ __launch_bounds__(128) void fc_head(
    const float* __restrict__ h2last, const float* __restrict__ fc1w,
    const float* __restrict__ fc1b, const float* __restrict__ fc2w,
    const float* __restrict__ fc2b, float* __restrict__ out) {
  __shared__ float hb[128];
  __shared__ float part[2];
  const int b = blockIdx.x, j = threadIdx.x;
  hb[j] = h2last[(size_t)b * HID + j];
  __syncthreads();
  const float* wr = fc1w + j * HID;
  float acc = 0.f;
  #pragma unroll 8
  for (int d = 0; d < HID; ++d) acc += wr[d] * hb[d];
  float v = fmaxf(acc + fc1b[j], 0.f) * fc2w[j];
  #pragma unroll
  for (int s = 32; s > 0; s >>= 1) v += __shfl_down(v, s);
  if ((j & 63) == 0) part[j >> 6] = v;
  __syncthreads();
  if (j == 0) out[b] = part[0] + part[1] + fc2b[0];
}

// -------------------------------------------------------------- launch ----
extern "C" void kernel_launch(void* const* d_in, const int* in_sizes, int n_in,
                              void* d_out, int out_size, void* d_ws, size_t ws_size,
                              hipStream_t stream) {
  const float* x    = (const float*)d_in[0];
  const float* Wih0 = (const float*)d_in[1];
  const float* Whh0 = (const float*)d_in[2];
  const float* bih0 = (const float*)d_in[3];
  const float* bhh0 = (const float*)d_in[4];
  const float* Wih1 = (const float*)d_in[5];
  const float* Whh1 = (const float*)d_in[6];
  const float* bih1 = (const float*)d_in[7];
  const float* bhh1 = (const float*)d_in[8];
  const float* fc1w = (const float*)d_in[9];
  const float* fc1b = (const float*)d_in[10];
  const float* fc2w = (const float*)d_in[11];
  const float* fc2b = (const float*)d_in[12];
  float* out = (float*)d_out;

  char* ws = (char*)d_ws;
  const size_t OFF_XH    = 0;                       // 512*512*64*2  = 32 MiB
  const size_t OFF_HS0   = 33554432;                // 512*512*128*2 = 64 MiB
  const size_t OFF_WC0   = OFF_HS0 + 67108864;      // 512*192*2
  const size_t OFF_WC1   = OFF_WC0 + 196608;        // 512*256*2
  const size_t OFF_B0    = OFF_WC1 + 262144;        // 512*4
  const size_t OFF_B1    = OFF_B0 + 2048;
  const size_t OFF_H2L   = OFF_B1 + 2048;           // 512*128*4

  _Float16* xh     = (_Float16*)(ws + OFF_XH);
  _Float16* hs0    = (_Float16*)(ws + OFF_HS0);
  _Float16* Wcat0  = (_Float16*)(ws + OFF_WC0);
  _Float16* Wcat1  = (_Float16*)(ws + OFF_WC1);
  float*    bias0  = (float*)(ws + OFF_B0);
  float*    bias1  = (float*)(ws + OFF_B1);
  float*    h2last = (float*)(ws + OFF_H2L);

  prep_x<<<16384, 256, 0, stream>>>(x, xh, 512 * 512 * 64 / 4);
  prep_w<<<512, 256, 0, stream>>>(Wih0, Whh0, bih0, bhh0, Wih1, Whh1, bih1, bhh1,
                                  Wcat0, Wcat1, bias0, bias1);
  lstm_l0<<<256, 512, 0, stream>>>(xh, Wcat0, bias0, hs0);
  lstm_l1<<<256, 512, 0, stream>>>(hs0, Wcat1, bias1, h2last);
  fc_head<<<512, 128, 0, stream>>>(h2last, fc1w, fc1b, fc2w, fc2b, out);
}

// Round 3
// 1055.466 us; speedup vs baseline: 1.8899x; 1.0974x over previous
//
#include <hip/hip_runtime.h>

#define T_STEPS 512
#define BATCH   512
#define HID     128

typedef _Float16 h2 __attribute__((ext_vector_type(2)));
typedef _Float16 h4 __attribute__((ext_vector_type(4)));
typedef _Float16 v8hf __attribute__((ext_vector_type(8)));
typedef float v4f __attribute__((ext_vector_type(4)));

__device__ __forceinline__ float rcpf(float x) {
#if __has_builtin(__builtin_amdgcn_rcpf)
  return __builtin_amdgcn_rcpf(x);
#else
  return 1.0f / x;
#endif
}
__device__ __forceinline__ float sigm(float x)  { return rcpf(1.0f + __expf(-x)); }
__device__ __forceinline__ float tanh_f(float x){ return 1.0f - 2.0f * rcpf(__expf(2.0f * x) + 1.0f); }

// ---------------------------------------------------------------- prep ----
__global__ __launch_bounds__(256) void prep_w(
    const float* __restrict__ Wih0, const float* __restrict__ Whh0,
    const float* __restrict__ bih0, const float* __restrict__ bhh0,
    const float* __restrict__ Wih1, const float* __restrict__ Whh1,
    const float* __restrict__ bih1, const float* __restrict__ bhh1,
    _Float16* __restrict__ Wcat0, _Float16* __restrict__ Wcat1,
    float* __restrict__ bias0, float* __restrict__ bias1) {
  int i = blockIdx.x * blockDim.x + threadIdx.x;
  if (i < 512 * 192) {                  // Wcat0 row r: [Wih0(64) | Whh0(128)]
    int r = i / 192, k = i - r * 192;
    float v = (k < 64) ? Wih0[r * 64 + k] : Whh0[r * 128 + (k - 64)];
    Wcat0[i] = (_Float16)v;
  }
  if (i < 512 * 256) {                  // Wcat1 row r: [Wih1(128) | Whh1(128)]
    int r = i >> 8, k = i & 255;
    float v = (k < 128) ? Wih1[r * 128 + k] : Whh1[r * 128 + (k - 128)];
    Wcat1[i] = (_Float16)v;
  }
  if (i < 512) {
    bias0[i] = bih0[i] + bhh0[i];
    bias1[i] = bih1[i] + bhh1[i];
  }
}

// ------------------------------------------------------------- layer 0 ----
// 256 blocks x 512 threads (8 waves), 2 chains/block. v = [x(64)|h(128)], K=192.
// Double-buffered vbuf; depth-2 global prefetch of x (fp32 -> fp16 in-kernel).
__global__ __launch_bounds__(512, 2) void lstm_l0(
    const float*    __restrict__ x,     // [B][T][64] fp32
    const _Float16* __restrict__ Wcat,  // [512][192]
    const float*    __restrict__ bias,  // [512]
    _Float16*       __restrict__ hs0) { // [B][T][128]
  __shared__ __align__(16) _Float16 vbuf[2][2][192];  // [buf][chain][x|h]
  __shared__ __align__(16) float gbuf[2][512];
  const int tid  = threadIdx.x;
  const int lane = tid & 63;
  const int wv   = tid >> 6;          // 0..7
  const int m    = lane & 15;         // A row within tile / B col (chain)
  const int q    = lane >> 4;         // k-group
  const int b0   = blockIdx.x * 2;

  // A fragments: af[i][kt], rt = 4*wv + i, K=192 (6 k-tiles)
  v8hf af[4][6];
  #pragma unroll
  for (int i = 0; i < 4; ++i) {
    const int rt = wv * 4 + i;
    #pragma unroll
    for (int kt = 0; kt < 6; ++kt)
      af[i][kt] = *(const v8hf*)&Wcat[(rt * 16 + m) * 192 + kt * 32 + q * 8];
  }
  // bias in MFMA C layout: row = (wv*4+i)*16 + q*4 + reg
  v4f cinit[4];
  #pragma unroll
  for (int i = 0; i < 4; ++i) {
    float4 b4 = *(const float4*)&bias[(wv * 4 + i) * 16 + q * 4];
    cinit[i][0] = b4.x; cinit[i][1] = b4.y; cinit[i][2] = b4.z; cinit[i][3] = b4.w;
  }

  const int sc = tid >> 7, sd = tid & 127;   // state mapping (tid<256)

  // prefetch lanes: waves 0,1 lanes 32..47 -> 32 ids; 16 lanes per chain x float4
  const bool ispf = (wv < 2) && (lane >= 32) && (lane < 48);
  const int  pid  = wv * 16 + (lane - 32);
  const int  pch  = (pid >> 4) & 1, poff = pid & 15;
  const float* pfbase = x + ((size_t)(b0 + pch) * T_STEPS) * 64 + poff * 4;

  if (tid < 256) vbuf[0][sc][64 + sd] = (_Float16)0.0f;   // h(-1) = 0
  float4 xreg;
  if (ispf) {
    float4 v0 = *(const float4*)(pfbase);            // x(0)
    h4 o; o[0] = (_Float16)v0.x; o[1] = (_Float16)v0.y;
          o[2] = (_Float16)v0.z; o[3] = (_Float16)v0.w;
    *(h4*)&vbuf[0][pch][poff * 4] = o;
    xreg = *(const float4*)(pfbase + 64);            // x(1)
  }
  __syncthreads();

  float c_state = 0.0f;

  for (int t = 0; t < T_STEPS; ++t) {
    const int p = t & 1, nb = p ^ 1;
    if (ispf) {
      if (t + 1 < T_STEPS) {                          // x(t+1): loaded a full step ago
        h4 o; o[0] = (_Float16)xreg.x; o[1] = (_Float16)xreg.y;
              o[2] = (_Float16)xreg.z; o[3] = (_Float16)xreg.w;
        *(h4*)&vbuf[nb][pch][poff * 4] = o;
      }
      if (t + 2 < T_STEPS)
        xreg = *(const float4*)(pfbase + (size_t)(t + 2) * 64);
    }

    v4f acc[4];
    #pragma unroll
    for (int i = 0; i < 4; ++i) acc[i] = cinit[i];
    #pragma unroll
    for (int kt = 0; kt < 6; ++kt) {
      v8hf bfr = *(const v8hf*)&vbuf[p][m & 1][kt * 32 + q * 8];
      #pragma unroll
      for (int i = 0; i < 4; ++i)
        acc[i] = __builtin_amdgcn_mfma_f32_16x16x32_f16(af[i][kt], bfr, acc[i], 0, 0, 0);
    }
    if (m < 2) {
      #pragma unroll
      for (int i = 0; i < 4; ++i) {
        float4 o; o.x = acc[i][0]; o.y = acc[i][1]; o.z = acc[i][2]; o.w = acc[i][3];
        *(float4*)&gbuf[m][(wv * 4 + i) * 16 + q * 4] = o;
      }
    }
    __syncthreads();                       // gates visible
    if (tid < 256) {
      const float gi = gbuf[sc][sd];
      const float gf = gbuf[sc][HID + sd];
      const float gg = gbuf[sc][2 * HID + sd];
      const float go = gbuf[sc][3 * HID + sd];
      c_state = sigm(gf) * c_state + sigm(gi) * tanh_f(gg);
      const float hval = sigm(go) * tanh_f(c_state);
      const _Float16 hh = (_Float16)hval;
      vbuf[nb][sc][64 + sd] = hh;
      hs0[((size_t)(b0 + sc) * T_STEPS + t) * HID + sd] = hh;
    }
    __syncthreads();                       // h(t), x(t+1) in buf nb complete
  }
}

// ------------------------------------------------------------- layer 1 ----
// v = [h0(128) | h1(128)], K=256 (8 k-tiles)
__global__ __launch_bounds__(512, 2) void lstm_l1(
    const _Float16* __restrict__ hs0,   // [B][T][128]
    const _Float16* __restrict__ Wcat,  // [512][256]
    const float*    __restrict__ bias,  // [512]
    float*          __restrict__ h2last) { // [B][128] fp32
  __shared__ __align__(16) _Float16 vbuf[2][2][256];
  __shared__ __align__(16) float gbuf[2][512];
  const int tid  = threadIdx.x;
  const int lane = tid & 63;
  const int wv   = tid >> 6;
  const int m    = lane & 15;
  const int q    = lane >> 4;
  const int b0   = blockIdx.x * 2;

  v8hf af[4][8];
  #pragma unroll
  for (int i = 0; i < 4; ++i) {
    const int rt = wv * 4 + i;
    #pragma unroll
    for (int kt = 0; kt < 8; ++kt)
      af[i][kt] = *(const v8hf*)&Wcat[(rt * 16 + m) * 256 + kt * 32 + q * 8];
  }
  v4f cinit[4];
  #pragma unroll
  for (int i = 0; i < 4; ++i) {
    float4 b4 = *(const float4*)&bias[(wv * 4 + i) * 16 + q * 4];
    cinit[i][0] = b4.x; cinit[i][1] = b4.y; cinit[i][2] = b4.z; cinit[i][3] = b4.w;
  }

  const int sc = tid >> 7, sd = tid & 127;

  // prefetch lanes: waves 0,1 lanes 32..47 -> 32 ids; 16 lanes per chain x 8 halfs
  const bool ispf = (wv < 2) && (lane >= 32) && (lane < 48);
  const int  pid  = wv * 16 + (lane - 32);
  const int  pch  = (pid >> 4) & 1, poff = pid & 15;
  const _Float16* pfbase = hs0 + ((size_t)(b0 + pch) * T_STEPS) * HID + poff * 8;

  if (tid < 256) vbuf[0][sc][HID + sd] = (_Float16)0.0f;   // h1(-1) = 0
  v8hf xreg;
  if (ispf) {
    *(v8hf*)&vbuf[0][pch][poff * 8] = *(const v8hf*)(pfbase);  // h0(0)
    xreg = *(const v8hf*)(pfbase + HID);                       // h0(1)
  }
  __syncthreads();

  float c_state = 0.0f;

  for (int t = 0; t < T_STEPS; ++t) {
    const int p = t & 1, nb = p ^ 1;
    if (ispf) {
      if (t + 1 < T_STEPS) *(v8hf*)&vbuf[nb][pch][poff * 8] = xreg;
      if (t + 2 < T_STEPS) xreg = *(const v8hf*)(pfbase + (size_t)(t + 2) * HID);
    }

    v4f acc[4];
    #pragma unroll
    for (int i = 0; i < 4; ++i) acc[i] = cinit[i];
    #pragma unroll
    for (int kt = 0; kt < 8; ++kt) {
      v8hf bfr = *(const v8hf*)&vbuf[p][m & 1][kt * 32 + q * 8];
      #pragma unroll
      for (int i = 0; i < 4; ++i)
        acc[i] = __builtin_amdgcn_mfma_f32_16x16x32_f16(af[i][kt], bfr, acc[i], 0, 0, 0);
    }
    if (m < 2) {
      #pragma unroll
      for (int i = 0; i < 4; ++i) {
        float4 o; o.x = acc[i][0]; o.y = acc[i][1]; o.z = acc[i][2]; o.w = acc[i][3];
        *(float4*)&gbuf[m][(wv * 4 + i) * 16 + q * 4] = o;
      }
    }
    __syncthreads();
    if (tid < 256) {
      const float gi = gbuf[sc][sd];
      const float gf = gbuf[sc][HID + sd];
      const float gg = gbuf[sc][2 * HID + sd];
      const float go = gbuf[sc][3 * HID + sd];
      c_state = sigm(gf) * c_state + sigm(gi) * tanh_f(gg);
      const float hval = sigm(go) * tanh_f(c_state);
      vbuf[nb][sc][HID + sd] = (_Float16)hval;
      if (t == T_STEPS - 1) h2last[(size_t)(b0 + sc) * HID + sd] = hval;
    }
    __syncthreads();
  }
}

// ------------------------------------------------------------- fc head ----
__global__ __launch_bounds__(128) void fc_head(
    const float* __restrict__ h2last, const float* __restrict__ fc1w,
    const float* __restrict__ fc1b, const float* __restrict__ fc2w,
    const float* __restrict__ fc2b, float* __restrict__ out) {
  __shared__ float hb[128];
  __shared__ float part[2];
  const int b = blockIdx.x, j = threadIdx.x;
  hb[j] = h2last[(size_t)b * HID + j];
  __syncthreads();
  const float* wr = fc1w + j * HID;
  float acc = 0.f;
  #pragma unroll 8
  for (int d = 0; d < HID; ++d) acc += wr[d] * hb[d];
  float v = fmaxf(acc + fc1b[j], 0.f) * fc2w[j];
  #pragma unroll
  for (int s = 32; s > 0; s >>= 1) v += __shfl_down(v, s);
  if ((j & 63) == 0) part[j >> 6] = v;
  __syncthreads();
  if (j == 0) out[b] = part[0] + part[1] + fc2b[0];
}

// -------------------------------------------------------------- launch ----
extern "C" void kernel_launch(void* const* d_in, const int* in_sizes, int n_in,
                              void* d_out, int out_size, void* d_ws, size_t ws_size,
                              hipStream_t stream) {
  const float* x    = (const float*)d_in[0];
  const float* Wih0 = (const float*)d_in[1];
  const float* Whh0 = (const float*)d_in[2];
  const float* bih0 = (const float*)d_in[3];
  const float* bhh0 = (const float*)d_in[4];
  const float* Wih1 = (const float*)d_in[5];
  const float* Whh1 = (const float*)d_in[6];
  const float* bih1 = (const float*)d_in[7];
  const float* bhh1 = (const float*)d_in[8];
  const float* fc1w = (const float*)d_in[9];
  const float* fc1b = (const float*)d_in[10];
  const float* fc2w = (const float*)d_in[11];
  const float* fc2b = (const float*)d_in[12];
  float* out = (float*)d_out;

  char* ws = (char*)d_ws;
  const size_t OFF_HS0 = 0;                         // 512*512*128*2 = 64 MiB
  const size_t OFF_WC0 = 67108864;                  // 512*192*2
  const size_t OFF_WC1 = OFF_WC0 + 196608;          // 512*256*2
  const size_t OFF_B0  = OFF_WC1 + 262144;          // 512*4
  const size_t OFF_B1  = OFF_B0 + 2048;
  const size_t OFF_H2L = OFF_B1 + 2048;             // 512*128*4

  _Float16* hs0    = (_Float16*)(ws + OFF_HS0);
  _Float16* Wcat0  = (_Float16*)(ws + OFF_WC0);
  _Float16* Wcat1  = (_Float16*)(ws + OFF_WC1);
  float*    bias0  = (float*)(ws + OFF_B0);
  float*    bias1  = (float*)(ws + OFF_B1);
  float*    h2last = (float*)(ws + OFF_H2L);

  prep_w<<<512, 256, 0, stream>>>(Wih0, Whh0, bih0, bhh0, Wih1, Whh1, bih1, bhh1,
                                  Wcat0, Wcat1, bias0, bias1);
  lstm_l0<<<256, 512, 0, stream>>>(x, Wcat0, bias0, hs0);
  lstm_l1<<<256, 512, 0, stream>>>(hs0, Wcat1, bias1, h2last);
  fc_head<<<512, 128, 0, stream>>>(h2last, fc1w, fc1b, fc2w, fc2b, out);
}